// Round 15
// baseline (228.890 us; speedup 1.0000x reference)
//
#include <hip/hip_runtime.h>
#include <math.h>

#define BATCH 8
#define SEQ   1024
#define HID   768
#define HEADS 6
#define DHEAD 64
#define ALLH  384   // HEADS*DHEAD
#define KS    9
#define PADC  4
#define MROWS (BATCH*SEQ)  // 8192

typedef __attribute__((ext_vector_type(8))) short bf16x8;
typedef __attribute__((ext_vector_type(4))) short bf16x4;
typedef __attribute__((ext_vector_type(4))) float f32x4;

__device__ __forceinline__ ushort f2bf(float x) {   // RTN-even f32 -> bf16 bits
    unsigned u = __float_as_uint(x);
    unsigned r = (u + 0x7FFFu + ((u >> 16) & 1u)) >> 16;
    return (ushort)r;
}
__device__ __forceinline__ unsigned pk2(float a, float b) {
    return (unsigned)f2bf(a) | ((unsigned)f2bf(b) << 16);
}
// TRANS ops via compiler-known paths (hazard handling) -- R7 lesson
__device__ __forceinline__ float fexp2(float x) {
#if __has_builtin(__builtin_amdgcn_exp2f)
    return __builtin_amdgcn_exp2f(x);
#else
    return exp2f(x);
#endif
}
__device__ __forceinline__ float fsqrt(float x) {
#if __has_builtin(__builtin_amdgcn_sqrtf)
    return __builtin_amdgcn_sqrtf(x);
#else
    return __sqrtf(x);
#endif
}
__device__ __forceinline__ unsigned cvtpk(float a, float b) {  // 2 bf16 in 1 instr (RNE, non-trans)
    unsigned r; asm("v_cvt_pk_bf16_f32 %0, %1, %2" : "=v"(r) : "v"(a), "v"(b)); return r;
}

__device__ __forceinline__ void mfma16(f32x4& c4, bf16x4 a, bf16x4 b) {
#if __has_builtin(__builtin_amdgcn_mfma_f32_16x16x16bf16_1k)
    c4 = __builtin_amdgcn_mfma_f32_16x16x16bf16_1k(a, b, c4, 0, 0, 0);
#else
    asm volatile("v_mfma_f32_16x16x16_bf16 %0, %1, %2, %0" : "+v"(c4) : "v"(a), "v"(b));
#endif
}

// ---------------- depthwise conv on K -> bf16, register sliding window ----------------
__global__ __launch_bounds__(256) void dconv_kernel(const float* __restrict__ Kin,
                                                    const float* __restrict__ dw,
                                                    ushort* __restrict__ y) {
    const int t = threadIdx.x;
    const int c4l = t & 63;
    const int sg = t >> 6;
    const int c4 = blockIdx.x * 64 + c4l;
    const int s0 = blockIdx.y * 64 + sg * 16;
    const int b = blockIdx.z;
    const int c = c4 * 4;

    const float* base = Kin + (size_t)b * SEQ * HID + c;
    ushort* ybase = y + (size_t)b * SEQ * HID + c;

    float wv[4][KS];
#pragma unroll
    for (int j = 0; j < 4; ++j)
#pragma unroll
        for (int tt = 0; tt < KS; ++tt) wv[j][tt] = dw[(c + j) * KS + tt];

    float4 win[KS];
#pragma unroll
    for (int tt = 0; tt < KS; ++tt) {
        int sj = s0 - PADC + tt;
        win[tt] = (sj >= 0 && sj < SEQ) ? *reinterpret_cast<const float4*>(base + (size_t)sj * HID)
                                        : float4{0.f, 0.f, 0.f, 0.f};
    }

#pragma unroll
    for (int i = 0; i < 16; ++i) {
        const int s = s0 + i;
        float4 acc = {0.f, 0.f, 0.f, 0.f};
#pragma unroll
        for (int tt = 0; tt < KS; ++tt) {
            acc.x += win[tt].x * wv[0][tt];
            acc.y += win[tt].y * wv[1][tt];
            acc.z += win[tt].z * wv[2][tt];
            acc.w += win[tt].w * wv[3][tt];
        }
        uint2 o;
        o.x = pk2(acc.x, acc.y); o.y = pk2(acc.z, acc.w);
        *reinterpret_cast<uint2*>(ybase + (size_t)s * HID) = o;
#pragma unroll
        for (int tt = 0; tt < KS - 1; ++tt) win[tt] = win[tt + 1];
        int sj = s + 1 + PADC;
        win[KS - 1] = (sj < SEQ) ? *reinterpret_cast<const float4*>(base + (size_t)sj * HID)
                                 : float4{0.f, 0.f, 0.f, 0.f};
    }
}

// ---------------- weight transpose-convert: W[768,384] f32 -> Wt[384,768] bf16 ----------------
__global__ __launch_bounds__(256) void wcvt_kernel(const float* __restrict__ W0, const float* __restrict__ W1,
                                                   const float* __restrict__ W2, const float* __restrict__ W3,
                                                   ushort* __restrict__ O0, ushort* __restrict__ O1,
                                                   ushort* __restrict__ O2, ushort* __restrict__ O3) {
    __shared__ float t[32][33];
    int wsel = blockIdx.z;
    const float* W = wsel == 0 ? W0 : wsel == 1 ? W1 : wsel == 2 ? W2 : W3;
    ushort* O = wsel == 0 ? O0 : wsel == 1 ? O1 : wsel == 2 ? O2 : O3;
    int kt = blockIdx.x * 32;
    int nt = blockIdx.y * 32;
    int tx = threadIdx.x & 31, ty = threadIdx.x >> 5;
#pragma unroll
    for (int i = 0; i < 4; ++i)
        t[ty + i * 8][tx] = W[(size_t)(kt + ty + i * 8) * ALLH + nt + tx];
    __syncthreads();
#pragma unroll
    for (int i = 0; i < 4; ++i)
        O[(size_t)(nt + ty + i * 8) * HID + kt + tx] = f2bf(t[tx][ty + i * 8]);
}

// ---------------- pw convert (already [N=384, K=768]) ----------------
__global__ __launch_bounds__(256) void pwcvt_kernel(const float* __restrict__ pw, ushort* __restrict__ pwb) {
    int i = blockIdx.x * 256 + threadIdx.x;
    if (i < ALLH * HID) pwb[i] = f2bf(pw[i]);
}

// ---------------- merged projection GEMMs, 64x64 tiles, early-issue prefetch ----------------
// 5 units x 768 blocks = 3840. unit: 0=Q->qb+qh, 1=K->khm tiles, 2=V@Wv->vhm tiles,
// 3=V@Wco->cob(+bco), 4=ybf@pw->kcb(+sep_bias).
// Loop = R13-proven two-barrier single-buffer shape; loads for step k+1 issued after
// barrier 2 of step k (in flight during compute) -- no new race surface.
__global__ __launch_bounds__(256) void gemm_all(const float* __restrict__ Q,
                                                const float* __restrict__ Kin,
                                                const float* __restrict__ V,
                                                const ushort* __restrict__ ybf,
                                                const ushort* __restrict__ WqT,
                                                const ushort* __restrict__ WkT,
                                                const ushort* __restrict__ WvT,
                                                const ushort* __restrict__ WcoT,
                                                const ushort* __restrict__ pwT,
                                                const float* __restrict__ bco,
                                                const float* __restrict__ sep_bias,
                                                float* __restrict__ qb,
                                                ushort* __restrict__ qh,
                                                ushort* __restrict__ khm,
                                                ushort* __restrict__ vhm,
                                                float* __restrict__ cob,
                                                float* __restrict__ kcb) {
    __shared__ __align__(16) ushort As[64 * 64];
    __shared__ __align__(16) ushort Bs[64 * 64];

    const int bx = blockIdx.x;
    const int swz = (bx & 7) * 480 + (bx >> 3);   // bijective: 3840 = 8*480
    const int unit = swz / 768;
    const int local = swz % 768;
    const int n0 = (local % 6) * 64;
    const int m0 = (local / 6) * 64;

    const float* Af = unit == 0 ? Q : unit == 1 ? Kin : V;   // units 0..3 f32
    const ushort* Ab = ybf;                                   // unit 4 bf16
    const ushort* Bt = unit == 0 ? WqT : unit == 1 ? WkT : unit == 2 ? WvT : unit == 3 ? WcoT : pwT;
    const bool af32 = (unit != 4);

    const int tid = threadIdx.x;
    const int lane = tid & 63;
    const int w = tid >> 6;
    const int g = lane >> 4;
    const int c = lane & 15;

    // staging geometry: thread owns rows r0 and r0+32 at k-chunk c8
    const int r0 = tid >> 3;
    const int r1 = r0 + 32;
    const int c8 = (tid & 7) * 8;
    const int b0 = r0 * 128 + ((c8 * 2) ^ ((r0 & 7) << 4));
    const int b1 = r1 * 128 + ((c8 * 2) ^ ((r1 & 7) << 4));

    uint4 ar0, ar1, br0, br1;
    float4 f0a, f0b, f1a, f1b;
    auto loadAB = [&](int k0) {
        if (af32) {
            f0a = *reinterpret_cast<const float4*>(&Af[(size_t)(m0 + r0) * HID + k0 + c8]);
            f0b = *reinterpret_cast<const float4*>(&Af[(size_t)(m0 + r0) * HID + k0 + c8 + 4]);
            f1a = *reinterpret_cast<const float4*>(&Af[(size_t)(m0 + r1) * HID + k0 + c8]);
            f1b = *reinterpret_cast<const float4*>(&Af[(size_t)(m0 + r1) * HID + k0 + c8 + 4]);
        } else {
            ar0 = *reinterpret_cast<const uint4*>(&Ab[(size_t)(m0 + r0) * HID + k0 + c8]);
            ar1 = *reinterpret_cast<const uint4*>(&Ab[(size_t)(m0 + r1) * HID + k0 + c8]);
        }
        br0 = *reinterpret_cast<const uint4*>(&Bt[(size_t)(n0 + r0) * HID + k0 + c8]);
        br1 = *reinterpret_cast<const uint4*>(&Bt[(size_t)(n0 + r1) * HID + k0 + c8]);
    };
    loadAB(0);

    f32x4 acc[4] = {{0,0,0,0},{0,0,0,0},{0,0,0,0},{0,0,0,0}};

    const int arow = w * 16 + c;
    const int asw = (arow & 7) << 4;

    for (int ks = 0; ks < 12; ++ks) {
        __syncthreads();                 // barrier 1: prev compute done reading LDS
        if (af32) {
            uint4 p0, p1;
            p0.x = pk2(f0a.x, f0a.y); p0.y = pk2(f0a.z, f0a.w);
            p0.z = pk2(f0b.x, f0b.y); p0.w = pk2(f0b.z, f0b.w);
            p1.x = pk2(f1a.x, f1a.y); p1.y = pk2(f1a.z, f1a.w);
            p1.z = pk2(f1b.x, f1b.y); p1.w = pk2(f1b.z, f1b.w);
            *reinterpret_cast<uint4*>((char*)As + b0) = p0;
            *reinterpret_cast<uint4*>((char*)As + b1) = p1;
        } else {
            *reinterpret_cast<uint4*>((char*)As + b0) = ar0;
            *reinterpret_cast<uint4*>((char*)As + b1) = ar1;
        }
        *reinterpret_cast<uint4*>((char*)Bs + b0) = br0;
        *reinterpret_cast<uint4*>((char*)Bs + b1) = br1;
        __syncthreads();                 // barrier 2: writes visible
        if (ks < 11) loadAB((ks + 1) * 64);   // issue next-step loads; hide under compute

        bf16x8 af0 = *reinterpret_cast<const bf16x8*>((char*)As + arow * 128 + ((g * 16) ^ asw));
        bf16x8 af1 = *reinterpret_cast<const bf16x8*>((char*)As + arow * 128 + ((64 + g * 16) ^ asw));
#pragma unroll
        for (int nq = 0; nq < 4; ++nq) {
            const int brow = nq * 16 + c;
            const int bsw = (brow & 7) << 4;
            bf16x8 bf0 = *reinterpret_cast<const bf16x8*>((char*)Bs + brow * 128 + ((g * 16) ^ bsw));
            bf16x8 bf1 = *reinterpret_cast<const bf16x8*>((char*)Bs + brow * 128 + ((64 + g * 16) ^ bsw));
            acc[nq] = __builtin_amdgcn_mfma_f32_16x16x32_bf16(af0, bf0, acc[nq], 0, 0, 0);
            acc[nq] = __builtin_amdgcn_mfma_f32_16x16x32_bf16(af1, bf1, acc[nq], 0, 0, 0);
        }
    }

    // ---------------- epilogues (R13-verbatim formulas) ----------------
    if (unit == 2) {
        // V@Wv -> transposed+swizzled 64x64 tiles [d-row][key-col]
        const int head = n0 >> 6;
        const int bb = m0 >> 10;
        const int st = (m0 & 1023) >> 6;
        char* tb = (char*)vhm + (((size_t)(bb * HEADS + head) * 16 + st) * 4096) * 2;
#pragma unroll
        for (int nq = 0; nq < 4; ++nq) {
            const int d = nq * 16 + c;
            unsigned off = (unsigned)d * 128 + (((unsigned)(32 * w + 8 * g)) ^ ((d & 7) << 4));
            uint2 vv;
            vv.x = pk2(acc[nq][0], acc[nq][1]);
            vv.y = pk2(acc[nq][2], acc[nq][3]);
            *reinterpret_cast<uint2*>(tb + off) = vv;
        }
        return;
    }

#pragma unroll
    for (int nq = 0; nq < 4; ++nq) {
        const int n = n0 + nq * 16 + c;
        float bv = 0.f;
        if (unit == 3) bv = bco[n];
        if (unit == 4) bv = sep_bias[n];
#pragma unroll
        for (int r = 0; r < 4; ++r) {
            const int m = m0 + w * 16 + g * 4 + r;
            float v = acc[nq][r] + bv;
            if (unit == 0) {
                qb[(size_t)m * ALLH + n] = v;
                int bb = m >> 10, s = m & 1023;
                int head = n >> 6, d = n & 63;
                qh[(((size_t)bb * HEADS + head) * SEQ + s) * 64 + d] = f2bf(v);
            } else if (unit == 1) {
                int bb = m >> 10, s = m & 1023;
                int head = n >> 6, d = n & 63;
                char* tb = (char*)khm + (((size_t)(bb * HEADS + head) * 16 + (s >> 6)) * 4096) * 2;
                unsigned off = (unsigned)(s & 63) * 128 + (((unsigned)(d * 2)) ^ ((s & 7) << 4));
                *reinterpret_cast<ushort*>(tb + off) = f2bf(v);
            } else if (unit == 3) {
                cob[(size_t)m * ALLH + n] = v;
            } else {  // unit 4
                kcb[(size_t)m * ALLH + n] = v;
            }
        }
    }
}

// ---------------- span kernel ----------------
__global__ __launch_bounds__(256) void spankern_kernel(const float* __restrict__ keyconv,
                                                       const float* __restrict__ q,
                                                       const float* __restrict__ Wck,
                                                       const float* __restrict__ bck,
                                                       float* __restrict__ kern_sm) {
    __shared__ float ca[4][ALLH];
    __shared__ float kv[4][64];
    int row0 = blockIdx.x * 4;
    int tid = threadIdx.x;
    int r = tid >> 6;
    int lane = tid & 63;
    int row = row0 + r;
    for (int e = lane; e < ALLH; e += 64) {
        size_t off = (size_t)row * ALLH + e;
        ca[r][e] = keyconv[off] * q[off];
    }
    __syncthreads();
    float val = 0.f;
    if (lane < HEADS * KS) {
        for (int kidx = 0; kidx < ALLH; ++kidx)
            val += ca[r][kidx] * Wck[kidx * (HEADS * KS) + lane];
        val += bck[lane];
    }
    kv[r][lane] = val;
    __syncthreads();
    if (lane < HEADS) {
        float mx = -INFINITY;
#pragma unroll
        for (int t = 0; t < KS; ++t) mx = fmaxf(mx, kv[r][lane * KS + t]);
        float e[KS];
        float sum = 0.f;
#pragma unroll
        for (int t = 0; t < KS; ++t) {
            e[t] = expf(kv[r][lane * KS + t] - mx);
            sum += e[t];
        }
        float inv = 1.f / sum;
#pragma unroll
        for (int t = 0; t < KS; ++t)
            kern_sm[((size_t)row * HEADS + lane) * KS + t] = e[t] * inv;
    }
}

// ---------------- conv_out ----------------
__global__ __launch_bounds__(256) void convout_kernel(const float* __restrict__ co,
                                                      const float* __restrict__ kern_sm,
                                                      float* __restrict__ out) {
    int idx = blockIdx.x * 256 + threadIdx.x;
    if (idx >= MROWS * (ALLH / 4)) return;
    int c4 = idx % (ALLH / 4);
    int s = (idx / (ALLH / 4)) % SEQ;
    int b = idx / ((ALLH / 4) * SEQ);
    int c = c4 * 4;
    int h = c >> 6;
    const float* ks = &kern_sm[(((size_t)b * SEQ + s) * HEADS + h) * KS];
    float kt[KS];
#pragma unroll
    for (int t = 0; t < KS; ++t) kt[t] = ks[t];
    float4 acc = {0.f, 0.f, 0.f, 0.f};
#pragma unroll
    for (int t = 0; t < KS; ++t) {
        int sj = s + t - PADC;
        if (sj >= 0 && sj < SEQ) {
            const float4 cv = *reinterpret_cast<const float4*>(&co[((size_t)b * SEQ + sj) * ALLH + c]);
            acc.x += cv.x * kt[t];
            acc.y += cv.y * kt[t];
            acc.z += cv.z * kt[t];
            acc.w += cv.w * kt[t];
        }
    }
    *reinterpret_cast<float4*>(&out[((size_t)b * SEQ + s) * (2 * ALLH) + ALLH + c]) = acc;
}

// ---------------- fused monotonic attention (MFMA, pre-swizzled tiles; verbatim R10/R12/R13) ----------------
__global__ __launch_bounds__(256) void attn_mfma(const ushort* __restrict__ qh,
                                                 const ushort* __restrict__ kh,
                                                 const ushort* __restrict__ vh,
                                                 const int* __restrict__ mask,
                                                 const float* __restrict__ gammas,
                                                 float* __restrict__ out) {
    __shared__ __align__(16) ushort kbuf[64 * 64];   // swizzled [key][d] tile (copied verbatim)
    __shared__ __align__(16) ushort vbuf[64 * 64];   // transposed+swizzled [d][key] tile
    __shared__ float s_msk[SEQ];

    const int bid = blockIdx.x;
    const int blk = (bid & 7) * 96 + (bid >> 3);
    const int qt = blk & 15;
    const int h = (blk >> 4) % HEADS;
    const int b = blk / (16 * HEADS);
    const int i0 = qt * 64;
    const int tid = threadIdx.x;
    const int lane = tid & 63;
    const int w = tid >> 6;
    const int g = lane >> 4;
    const int c = lane & 15;

    const float LOG2E = 1.44269504f;
    float g0 = gammas[h];
    float gamma2 = -(fmaxf(g0, 0.f) + log1pf(expf(-fabsf(g0)))) * LOG2E;  // -softplus * log2e
    const float SLOG2 = 0.125f * LOG2E;

    const ushort* ktiles = kh + ((size_t)(b * HEADS + h) * 16) * 4096;
    const ushort* vtiles = vh + ((size_t)(b * HEADS + h) * 16) * 4096;
    const ushort* qhb = qh + ((size_t)b * HEADS + h) * SEQ * 64;

    for (int e = tid; e < SEQ; e += 256)
        s_msk[e] = (mask[b * SEQ + e] != 0) ? 1.f : 0.f;

    // Q B-fragments
    bf16x8 qf0, qf1;
    {
        const ushort* qrow = qhb + (size_t)(i0 + w * 16 + c) * 64 + g * 8;
        qf0 = *reinterpret_cast<const bf16x8*>(qrow);
        qf1 = *reinterpret_cast<const bf16x8*>(qrow + 32);
    }

    // ================= pass 1: raw denominator T =================
    float Tacc = 0.f;
    for (int chk = 0; chk < 16; ++chk) {
        __syncthreads();
        const ushort* ktp = ktiles + chk * 4096;
#pragma unroll
        for (int it = 0; it < 2; ++it) {
            int e16 = (tid + it * 256) * 16;
            *reinterpret_cast<uint4*>((char*)kbuf + e16) =
                *reinterpret_cast<const uint4*>((const char*)ktp + e16);
        }
        __syncthreads();
        const int j0 = chk * 64;
#pragma unroll
        for (int m = 0; m < 4; ++m) {
            f32x4 acc = {0.f, 0.f, 0.f, 0.f};
            int row = m * 16 + c;
            int sw = (row & 7) << 4;
            bf16x8 kf0 = *reinterpret_cast<const bf16x8*>((char*)kbuf + row * 128 + ((g * 16) ^ sw));
            bf16x8 kf1 = *reinterpret_cast<const bf16x8*>((char*)kbuf + row * 128 + ((64 + g * 16) ^ sw));
            acc = __builtin_amdgcn_mfma_f32_16x16x32_bf16(kf0, qf0, acc, 0, 0, 0);
            acc = __builtin_amdgcn_mfma_f32_16x16x32_bf16(kf1, qf1, acc, 0, 0, 0);
#pragma unroll
            for (int r = 0; r < 4; ++r) {
                float mk = s_msk[j0 + m * 16 + g * 4 + r];
                Tacc += mk * fexp2(acc[r] * SLOG2);
            }
        }
    }
    Tacc += __shfl_xor(Tacc, 16, 64);
    Tacc += __shfl_xor(Tacc, 32, 64);
    const float T = Tacc;
    const float invT = (T > 0.f) ? 1.f / T : 0.f;

    // ================= pass 2: cum, effect, second softmax, PV =================
    f32x4 ctx0 = {0,0,0,0}, ctx1 = {0,0,0,0}, ctx2 = {0,0,0,0}, ctx3 = {0,0,0,0};
    float l2acc = 0.f;
    float base = 0.f;
    const float iq = (float)(i0 + w * 16 + c);
    const unsigned vx = (unsigned)((c & 7) << 4);    // lane-const read swizzle

    for (int chk = 0; chk < 16; ++chk) {
        __syncthreads();
        const ushort* ktp = ktiles + chk * 4096;
        const ushort* vtp = vtiles + chk * 4096;
#pragma unroll
        for (int it = 0; it < 2; ++it) {
            int e16 = (tid + it * 256) * 16;
            *reinterpret_cast<uint4*>((char*)kbuf + e16) =
                *reinterpret_cast<const uint4*>((const char*)ktp + e16);
            *reinterpret_cast<uint4*>((char*)vbuf + e16) =
                *reinterpret_cast<const uint4*>((const char*)vtp + e16);
        }
        __syncthreads();
        const int j0 = chk * 64;
#pragma unroll
        for (int m = 0; m < 4; ++m) {
            f32x4 acc = {0.f, 0.f, 0.f, 0.f};
            int row = m * 16 + c;
            int sw = (row & 7) << 4;
            bf16x8 kf0 = *reinterpret_cast<const bf16x8*>((char*)kbuf + row * 128 + ((g * 16) ^ sw));
            bf16x8 kf1 = *reinterpret_cast<const bf16x8*>((char*)kbuf + row * 128 + ((64 + g * 16) ^ sw));
            acc = __builtin_amdgcn_mfma_f32_16x16x32_bf16(kf0, qf0, acc, 0, 0, 0);
            acc = __builtin_amdgcn_mfma_f32_16x16x32_bf16(kf1, qf1, acc, 0, 0, 0);

            float sl[4], mk[4], incl[4];
            float li = 0.f;
#pragma unroll
            for (int r = 0; r < 4; ++r) {
                mk[r] = s_msk[j0 + m * 16 + g * 4 + r];
                sl[r] = acc[r] * SLOG2;                 // score in log2 units
                float e = mk[r] * fexp2(sl[r]);
                li += e;
                incl[r] = li;
            }
            float gs = li;
            float up = __shfl_up(gs, 16, 64); if (g >= 1) gs += up;
            up = __shfl_up(gs, 32, 64); if (g >= 2) gs += up;
            float gexcl = gs - li;
            float ttot = __shfl(gs, 48 + c, 64);

            const float dbase = iq - (float)(j0 + m * 16 + g * 4);
            float p2[4];
#pragma unroll
            for (int r = 0; r < 4; ++r) {
                float cum = base + gexcl + incl[r];
                float rem = fmaxf(1.0f - cum * invT, 0.f);
                float pos = fabsf(dbase - (float)r);
                float dist = fsqrt(rem * pos);
                float eff = fmaxf(fexp2(dist * gamma2), 1e-5f);  // gamma2<0, dist>=0 -> eff<=1
                p2[r] = mk[r] * fexp2(sl[r] * eff);
                l2acc += p2[r];
            }
            base += ttot;

            union { uint2 u; bf16x4 v; } pu;
            pu.u.x = cvtpk(p2[0], p2[1]);
            pu.u.y = cvtpk(p2[2], p2[3]);
            bf16x4 pa = pu.v;

            const unsigned cb = ((unsigned)(32 * m + 8 * g)) ^ vx;
#pragma unroll
            for (int t = 0; t < 4; ++t) {
                bf16x4 vfrag = *reinterpret_cast<const bf16x4*>((char*)vbuf + (unsigned)(c + 16 * t) * 128 + cb);
                if (t == 0) mfma16(ctx0, pa, vfrag);
                else if (t == 1) mfma16(ctx1, pa, vfrag);
                else if (t == 2) mfma16(ctx2, pa, vfrag);
                else mfma16(ctx3, pa, vfrag);
            }
        }
    }
    l2acc += __shfl_xor(l2acc, 16, 64);
    l2acc += __shfl_xor(l2acc, 32, 64);
    const float invl2 = 1.f / l2acc;

#pragma unroll
    for (int r = 0; r < 4; ++r) {
        float inv_r = __shfl(invl2, g * 4 + r, 64);
        int qrow = i0 + w * 16 + g * 4 + r;
        float* orow = out + ((size_t)b * SEQ + qrow) * (2 * ALLH) + h * DHEAD;
        orow[c +  0] = ctx0[r] * inv_r;
        orow[c + 16] = ctx1[r] * inv_r;
        orow[c + 32] = ctx2[r] * inv_r;
        orow[c + 48] = ctx3[r] * inv_r;
    }
}

// ---------------- launch ----------------
extern "C" void kernel_launch(void* const* d_in, const int* in_sizes, int n_in,
                              void* d_out, int out_size, void* d_ws, size_t ws_size,
                              hipStream_t stream) {
    const float* Q = (const float*)d_in[0];
    const float* Kin = (const float*)d_in[1];
    const float* V = (const float*)d_in[2];
    const float* Wq = (const float*)d_in[3];
    const float* Wk = (const float*)d_in[4];
    const float* Wv = (const float*)d_in[5];
    const float* dw = (const float*)d_in[6];
    const float* pw = (const float*)d_in[7];
    const float* sep_bias = (const float*)d_in[8];
    const float* Wck = (const float*)d_in[9];
    const float* bck = (const float*)d_in[10];
    const float* Wco = (const float*)d_in[11];
    const float* bco = (const float*)d_in[12];
    const float* gammas = (const float*)d_in[13];
    const int* mask = (const int*)d_in[14];
    float* out = (float*)d_out;
    float* ws = (float*)d_ws;

    const size_t NP = (size_t)MROWS * ALLH;        // 3145728
    const size_t WSZ = (size_t)ALLH * HID;         // 294912
    float* qb   = ws;                              // f32 q (spankern)
    float* cob  = qb + NP;
    float* kcb  = cob + NP;
    float* kern = kcb + NP;                        // 8192*54
    ushort* qh  = (ushort*)(kern + (size_t)MROWS * HEADS * KS);
    ushort* khm = qh + NP;                         // swizzled K tiles
    ushort* vhm = khm + NP;                        // transposed+swizzled V tiles
    ushort* ybf = vhm + NP;                        // dconv out bf16 [8192][768]
    ushort* WqT = ybf + (size_t)MROWS * HID;
    ushort* WkT = WqT + WSZ;
    ushort* WvT = WkT + WSZ;
    ushort* WcoT = WvT + WSZ;
    ushort* pwT = WcoT + WSZ;

    // 1. depthwise conv (register sliding window) + weight conversions
    dconv_kernel<<<dim3(3, 16, BATCH), 256, 0, stream>>>(Kin, dw, ybf);
    wcvt_kernel<<<dim3(24, 12, 4), 256, 0, stream>>>(Wq, Wk, Wv, Wco, WqT, WkT, WvT, WcoT);
    pwcvt_kernel<<<(ALLH * HID + 255) / 256, 256, 0, stream>>>(pw, pwT);

    // 2. all five projection GEMMs in one 64x64-tile dispatch with early-issue prefetch
    gemm_all<<<3840, 256, 0, stream>>>(Q, Kin, V, ybf, WqT, WkT, WvT, WcoT, pwT,
                                       bco, sep_bias, qb, qh, khm, vhm, cob, kcb);

    // 3. span-dynamic-conv kernel weights + softmax
    spankern_kernel<<<MROWS / 4, 256, 0, stream>>>(kcb, qb, Wck, bck, kern);

    // 4. conv branch output (channels 384..767)
    convout_kernel<<<(MROWS * (ALLH / 4) + 255) / 256, 256, 0, stream>>>(cob, kern, out);

    // 5. fused monotonic attention (channels 0..383)
    attn_mfma<<<BATCH * HEADS * (SEQ / 64), 256, 0, stream>>>(qh, khm, vhm, mask, gammas, out);
}